// Round 3
// baseline (864.608 us; speedup 1.0000x reference)
//
#include <hip/hip_runtime.h>
#include <hip/hip_bf16.h>

// AxialAttention on MI355X — bf16 MFMA pipeline.
// K1: per (n0,w) block: stage x->LDS bf16; per head: VALU QKV -> E^T = K*Q^T
//     (mfma_32x32x16) -> in-register softmax sums -> PV^T (mfma_16x16x32) -> AO bf16.
// K2: out-proj per (n0,s): D[e][w] = Wo * AO^T via mfma_32x32x16, +bias, fp32 out.

typedef __attribute__((ext_vector_type(8)))  short bf16x8;
typedef __attribute__((ext_vector_type(4)))  float f32x4;
typedef __attribute__((ext_vector_type(16))) float f32x16;

__device__ __forceinline__ float bf2f(unsigned short u) {
    union { unsigned int i; float f; } c; c.i = ((unsigned int)u) << 16; return c.f;
}
__device__ __forceinline__ unsigned short f2bf(float f) {
    union { __hip_bfloat16 h; unsigned short u; } c; c.h = __float2bfloat16(f); return c.u;
}

#define INV_SCALE 0.088388347648318447f   // 1/sqrt(128)

__global__ __launch_bounds__(256, 2) void axattn_qkvattn(
    const float* __restrict__ x,
    const float* __restrict__ Wq,
    const float* __restrict__ Wk,
    const float* __restrict__ Wv,
    unsigned short* __restrict__ AO)   // bf16 out [b][s][c]
{
    __shared__ __align__(16) unsigned short y_s[128][136];  // [s][c] bf16, pad->conflict-free
    __shared__ __align__(16) unsigned short q_s[128][24];   // [s][e]
    __shared__ __align__(16) unsigned short k_s[128][24];   // [s][e]
    __shared__ __align__(16) unsigned short vT_s[16][136];  // [d][j]
    __shared__ __align__(16) unsigned short pT_s[4][32][40];// per-wave [s_local][j_local]

    // swizzle: bb = g*8 + r (r = XCD). n0 = g>>4, wm = g&15, w = 16r + wm
    // -> the 16 blocks sharing each 64B x line are consecutive on one XCD.
    int bb = blockIdx.x;
    int r  = bb & 7;
    int g  = bb >> 3;
    int n0 = g >> 4;
    int w  = 16 * r + (g & 15);

    int tid  = threadIdx.x;
    int lane = tid & 63;
    int wi   = tid >> 6;

    // ---- stage x -> y_s (bf16) ----
    const float* xb = x + ((size_t)n0 * 128 * 128 * 128) + w;
    #pragma unroll
    for (int ii = 0; ii < 4; ++ii) {
        float tmp[16];
        #pragma unroll
        for (int j = 0; j < 16; ++j) {
            int idx = tid + 256 * (ii * 16 + j);
            tmp[j] = xb[((size_t)(idx & 127) * 128 + (idx >> 7)) * 128];
        }
        #pragma unroll
        for (int j = 0; j < 16; ++j) {
            int idx = tid + 256 * (ii * 16 + j);
            y_s[idx >> 7][idx & 127] = f2bf(tmp[j]);
        }
    }
    __syncthreads();

    for (int h = 0; h < 8; ++h) {
        // ---- QKV (VALU): thread -> (s = tid&127, eh = tid>>7); eh is wave-uniform ----
        {
            int s  = tid & 127;
            int eh = tid >> 7;
            float yv[16];
            union { unsigned short u[8]; int4 v; } ya, yb;
            ya.v = *(const int4*)&y_s[s][16 * h];
            yb.v = *(const int4*)&y_s[s][16 * h + 8];
            #pragma unroll
            for (int d = 0; d < 8; ++d) { yv[d] = bf2f(ya.u[d]); yv[d + 8] = bf2f(yb.u[d]); }

            float qa[8], ka[8], va[8];
            #pragma unroll
            for (int j = 0; j < 8; ++j) { qa[j] = 0.f; ka[j] = 0.f; va[j] = 0.f; }
            #pragma unroll
            for (int d = 0; d < 16; ++d) {
                float yd = yv[d];
                #pragma unroll
                for (int j = 0; j < 8; ++j) {
                    int e = 8 * eh + j;
                    qa[j] = fmaf(yd, Wq[e * 16 + d], qa[j]);
                    ka[j] = fmaf(yd, Wk[e * 16 + d], ka[j]);
                    va[j] = fmaf(yd, Wv[e * 16 + d], va[j]);
                }
            }
            union { unsigned short u[8]; int4 v; } pq, pk;
            #pragma unroll
            for (int j = 0; j < 8; ++j) {
                pq.u[j] = f2bf(qa[j] * INV_SCALE);
                pk.u[j] = f2bf(ka[j]);
            }
            *(int4*)&q_s[s][8 * eh] = pq.v;
            *(int4*)&k_s[s][8 * eh] = pk.v;
            #pragma unroll
            for (int j = 0; j < 8; ++j) vT_s[8 * eh + j][s] = f2bf(va[j]);
        }
        __syncthreads();

        // ---- E^T = K * Q^T for this wave's 32 s-columns ----
        int sl = lane & 31;          // s-local
        int kh = lane >> 5;          // k-half (e 0..7 / 8..15)
        bf16x8 qfrag = *(bf16x8*)&q_s[32 * wi + sl][8 * kh];

        f32x16 eacc[4];
        #pragma unroll
        for (int jt = 0; jt < 4; ++jt) {
            f32x16 z;
            #pragma unroll
            for (int i = 0; i < 16; ++i) z[i] = 0.f;
            bf16x8 kfrag = *(bf16x8*)&k_s[32 * jt + sl][8 * kh];
            eacc[jt] = __builtin_amdgcn_mfma_f32_32x32x16_bf16(kfrag, qfrag, z, 0, 0, 0);
        }

        // ---- softmax pieces: exp in place, in-register row sum over j ----
        float s8[8];
        #pragma unroll
        for (int a = 0; a < 8; ++a) {
            float u = 0.f;
            #pragma unroll
            for (int b = 0; b < 8; ++b) {
                int jt = (a * 8 + b) >> 4, rg = (a * 8 + b) & 15;
                float p = __expf(eacc[jt][rg]);
                eacc[jt][rg] = p;
                u += p;
            }
            s8[a] = u;
        }
        float lsum = ((s8[0] + s8[1]) + (s8[2] + s8[3])) + ((s8[4] + s8[5]) + (s8[6] + s8[7]));
        lsum += __shfl_xor(lsum, 32, 64);
        float rl = 1.0f / lsum;

        // ---- PV^T: per 32-j tile, roundtrip P through small LDS slot ----
        f32x4 ao0, ao1;
        #pragma unroll
        for (int i = 0; i < 4; ++i) { ao0[i] = 0.f; ao1[i] = 0.f; }

        int qd = lane >> 4;          // quad 0..3
        #pragma unroll
        for (int jt = 0; jt < 4; ++jt) {
            // pack pairs: regs (4a+b, 4a+b+1), b in {0,2}: j_local = 8a + b + 4*kh
            #pragma unroll
            for (int a = 0; a < 4; ++a) {
                #pragma unroll
                for (int b = 0; b < 4; b += 2) {
                    int r0 = 4 * a + b;
                    unsigned int lo = f2bf(eacc[jt][r0]);
                    unsigned int hi = f2bf(eacc[jt][r0 + 1]);
                    int j0 = 8 * a + b + 4 * kh;
                    *(unsigned int*)&pT_s[wi][sl][j0] = lo | (hi << 16);
                }
            }
            // wave-private RAW: compiler inserts lgkmcnt wait
            bf16x8 afrag = *(bf16x8*)&vT_s[lane & 15][32 * jt + 8 * qd];
            bf16x8 b0 = *(bf16x8*)&pT_s[wi][lane & 15][8 * qd];
            bf16x8 b1 = *(bf16x8*)&pT_s[wi][16 + (lane & 15)][8 * qd];
            ao0 = __builtin_amdgcn_mfma_f32_16x16x32_bf16(afrag, b0, ao0, 0, 0, 0);
            ao1 = __builtin_amdgcn_mfma_f32_16x16x32_bf16(afrag, b1, ao1, 0, 0, 0);
        }

        // ---- scale by 1/l and store AO (bf16) ----
        #pragma unroll
        for (int nt = 0; nt < 2; ++nt) {
            float rr = __shfl(rl, 16 * nt + (lane & 15), 64);
            int sg = 32 * wi + 16 * nt + (lane & 15);
            size_t base = (((size_t)(n0 * 128 + w) * 128) + sg) * 128 + 16 * h;
            const f32x4& acc = nt ? ao1 : ao0;
            #pragma unroll
            for (int rg = 0; rg < 4; ++rg) {
                int d = 4 * qd + rg;
                AO[base + d] = f2bf(acc[rg] * rr);
            }
        }
        __syncthreads();   // protect q_s/k_s/vT_s before next head's QKV
    }
}

// out[n0][e][s][w] = sum_c Wo[e][c] * AO[(n0*128+w)][s][c] + bo[e]
__global__ __launch_bounds__(256, 2) void axattn_proj(
    const unsigned short* __restrict__ AO,
    const float* __restrict__ Wo,
    const float* __restrict__ bo,
    float* __restrict__ out)
{
    __shared__ __align__(16) unsigned short ao_s[128][136];  // [w][c]

    int n0 = blockIdx.x >> 7;
    int s  = blockIdx.x & 127;
    int tid = threadIdx.x, lane = tid & 63, wi = tid >> 6;   // wi = e m-tile

    // stage AO[w][c] rows (bf16, b128)
    #pragma unroll
    for (int i = 0; i < 8; ++i) {
        int idx = tid + 256 * i;
        int ww = idx >> 4;
        int ch = idx & 15;
        *(int4*)&ao_s[ww][8 * ch] =
            *(const int4*)(AO + (((size_t)(n0 * 128 + ww) * 128) + s) * 128 + 8 * ch);
    }
    __syncthreads();

    int m  = lane & 31;
    int kh = lane >> 5;
    int e  = 32 * wi + m;

    f32x16 acc[4];
    #pragma unroll
    for (int nt = 0; nt < 4; ++nt) {
        #pragma unroll
        for (int i = 0; i < 16; ++i) acc[nt][i] = 0.f;
    }

    #pragma unroll
    for (int kt = 0; kt < 8; ++kt) {
        int c0 = 16 * kt + 8 * kh;
        const float4* wp = (const float4*)(Wo + (size_t)e * 128 + c0);
        float4 wA = wp[0], wB = wp[1];
        union { unsigned short u[8]; bf16x8 v; } af;
        af.u[0] = f2bf(wA.x); af.u[1] = f2bf(wA.y); af.u[2] = f2bf(wA.z); af.u[3] = f2bf(wA.w);
        af.u[4] = f2bf(wB.x); af.u[5] = f2bf(wB.y); af.u[6] = f2bf(wB.z); af.u[7] = f2bf(wB.w);
        #pragma unroll
        for (int nt = 0; nt < 4; ++nt) {
            bf16x8 bfrag = *(bf16x8*)&ao_s[32 * nt + m][c0];
            acc[nt] = __builtin_amdgcn_mfma_f32_32x32x16_bf16(af.v, bfrag, acc[nt], 0, 0, 0);
        }
    }

    // epilogue: +bias, coalesced fp32 stores
    #pragma unroll
    for (int rg = 0; rg < 16; ++rg) {
        int er = 32 * wi + (rg & 3) + 8 * (rg >> 2) + 4 * kh;
        float bv = bo[er];
        size_t rowbase = (((size_t)(n0 * 128 + er) * 128) + s) * 128;
        #pragma unroll
        for (int nt = 0; nt < 4; ++nt) {
            out[rowbase + 32 * nt + m] = acc[nt][rg] + bv;
        }
    }
}

extern "C" void kernel_launch(void* const* d_in, const int* in_sizes, int n_in,
                              void* d_out, int out_size, void* d_ws, size_t ws_size,
                              hipStream_t stream) {
    const float* x  = (const float*)d_in[0];
    const float* Wq = (const float*)d_in[1];
    const float* Wk = (const float*)d_in[2];
    const float* Wv = (const float*)d_in[3];
    const float* Wo = (const float*)d_in[4];
    const float* bo = (const float*)d_in[5];
    float* out = (float*)d_out;
    unsigned short* AO = (unsigned short*)d_ws;   // 32 MiB bf16 [b][s][c]

    axattn_qkvattn<<<1024, 256, 0, stream>>>(x, Wq, Wk, Wv, AO);
    axattn_proj<<<1024, 256, 0, stream>>>(AO, Wo, bo, out);
}